// Round 2
// baseline (125.894 us; speedup 1.0000x reference)
//
#include <hip/hip_runtime.h>
#include <hip/hip_bf16.h>

typedef unsigned int uint32;
typedef unsigned short u16;

#define NPT 128        // grid nodes per dim
#define RNK 16         // TT rank
#define MIDROW 264     // bf16 elems per LDS row for mid core (256 + 8 pad) = 528 B
#define MIDROW_U32 132
#define EROW 24        // bf16 elems per edge row (16 + 8 pad) = 48 B

#define MID_ELEMS (NPT*MIDROW)      // 33792 u16
#define EDGE_ELEMS (NPT*EROW)       // 3072 u16
// ws image layout (u16 offsets): [c1 33792][e0 3072][e3 3072][c2 33792]
#define IMG_C1 0
#define IMG_E0 33792
#define IMG_E3 36864
#define IMG_C2 39936
#define IMG_TOTAL 73728
#define WS_BYTES (IMG_TOTAL*2)      // 147456 B

#define SMEM_BYTES (MID_ELEMS*2 + 2*EDGE_ELEMS*2)   // 67584 + 12288 = 79872 B
#define PHASE0_CHUNKS (SMEM_BYTES/1024)             // 78 x 1KiB wave-chunks
#define PHASE1_CHUNKS (MID_ELEMS*2/1024)            // 66

#if defined(__has_builtin)
#if __has_builtin(__builtin_amdgcn_fdot2_f32_bf16)
#define HAVE_BFDOT2 1
#endif
#endif

__device__ __forceinline__ float bl(uint32 u){ return __uint_as_float(u << 16); }
__device__ __forceinline__ float bh(uint32 u){ return __uint_as_float(u & 0xffff0000u); }

__device__ __forceinline__ uint32 pk2(float a, float b){
  __hip_bfloat16 l = __float2bfloat16(a);
  __hip_bfloat16 h = __float2bfloat16(b);
  return (uint32)(*(u16*)&l) | ((uint32)(*(u16*)&h) << 16);
}

#ifdef HAVE_BFDOT2
typedef __bf16 v2bf __attribute__((ext_vector_type(2)));
__device__ __forceinline__ v2bf bc(uint32 u){ return __builtin_bit_cast(v2bf, u); }

// dot of packed-bf16 v (8 u32) with 16 bf16 core elems in two uint4
__device__ __forceinline__ float dot16b(const uint32* vp, uint4 U0, uint4 U1) {
  float s0 = 0.f, s1 = 0.f;
  s0 = __builtin_amdgcn_fdot2_f32_bf16(bc(vp[0]), bc(U0.x), s0, false);
  s0 = __builtin_amdgcn_fdot2_f32_bf16(bc(vp[1]), bc(U0.y), s0, false);
  s0 = __builtin_amdgcn_fdot2_f32_bf16(bc(vp[2]), bc(U0.z), s0, false);
  s0 = __builtin_amdgcn_fdot2_f32_bf16(bc(vp[3]), bc(U0.w), s0, false);
  s1 = __builtin_amdgcn_fdot2_f32_bf16(bc(vp[4]), bc(U1.x), s1, false);
  s1 = __builtin_amdgcn_fdot2_f32_bf16(bc(vp[5]), bc(U1.y), s1, false);
  s1 = __builtin_amdgcn_fdot2_f32_bf16(bc(vp[6]), bc(U1.z), s1, false);
  s1 = __builtin_amdgcn_fdot2_f32_bf16(bc(vp[7]), bc(U1.w), s1, false);
  return s0 + s1;
}
#else
__device__ __forceinline__ float dot16(const float* v, uint4 U0, uint4 U1) {
  float s0 = fmaf(v[1],  bh(U0.x), v[0]*bl(U0.x));
  s0 = fmaf(v[2],  bl(U0.y), s0); s0 = fmaf(v[3],  bh(U0.y), s0);
  float s1 = fmaf(v[5],  bh(U0.z), v[4]*bl(U0.z));
  s1 = fmaf(v[6],  bl(U0.w), s1); s1 = fmaf(v[7],  bh(U0.w), s1);
  float s2 = fmaf(v[9],  bh(U1.x), v[8]*bl(U1.x));
  s2 = fmaf(v[10], bl(U1.y), s2); s2 = fmaf(v[11], bh(U1.y), s2);
  float s3 = fmaf(v[13], bh(U1.z), v[12]*bl(U1.z));
  s3 = fmaf(v[14], bl(U1.w), s3); s3 = fmaf(v[15], bh(U1.w), s3);
  return (s0 + s1) + (s2 + s3);
}
#endif

// lerp 8 bf16 pairs (lo,hi packed in uint4) -> fp32
__device__ __forceinline__ void lerp8(uint4 lo, uint4 hi, float w, float* o) {
  o[0] = fmaf(w, bl(hi.x) - bl(lo.x), bl(lo.x));
  o[1] = fmaf(w, bh(hi.x) - bh(lo.x), bh(lo.x));
  o[2] = fmaf(w, bl(hi.y) - bl(lo.y), bl(lo.y));
  o[3] = fmaf(w, bh(hi.y) - bh(lo.y), bh(lo.y));
  o[4] = fmaf(w, bl(hi.z) - bl(lo.z), bl(lo.z));
  o[5] = fmaf(w, bh(hi.z) - bh(lo.z), bh(lo.z));
  o[6] = fmaf(w, bl(hi.w) - bl(lo.w), bl(lo.w));
  o[7] = fmaf(w, bh(hi.w) - bh(lo.w), bh(lo.w));
}

__device__ __forceinline__ float remap_clamp(float x) {
  float xr = (x + 1.0f) * 0.5f * (float)(NPT - 1);
  return fminf(fmaxf(xr, 0.0f), (float)(NPT - 1));
}

// one middle-dim contraction: v <- v @ ((1-w)*Lo + w*Hi), core rows in LDS as [n][j*16+i] bf16
__device__ __forceinline__ void tt_mid(const uint32* __restrict__ base, float xc, float v[16]) {
  int n0 = (int)xc;
  float w = xc - (float)n0;
  int n1 = min(n0 + 1, NPT - 1);
  const uint32* r0 = base + n0 * MIDROW_U32;
  const uint32* r1 = base + n1 * MIDROW_U32;

#ifdef HAVE_BFDOT2
  uint32 vp[8];
#pragma unroll
  for (int k = 0; k < 8; ++k) vp[k] = pk2(v[2*k], v[2*k+1]);
#endif

  float nv[16];
#pragma unroll
  for (int j = 0; j < 16; ++j) {
    const uint4* p0 = (const uint4*)(r0 + j * 8);
    const uint4* p1 = (const uint4*)(r1 + j * 8);
    uint4 A0 = p0[0], A1 = p0[1];
    uint4 B0 = p1[0], B1 = p1[1];
#ifdef HAVE_BFDOT2
    float a = dot16b(vp, A0, A1);
    float b = dot16b(vp, B0, B1);
#else
    float a = dot16(v, A0, A1);
    float b = dot16(v, B0, B1);
#endif
    nv[j] = fmaf(w, b - a, a);
  }
#pragma unroll
  for (int j = 0; j < 16; ++j) v[j] = nv[j];
}

// ---------------- prep kernel: fp32 cores -> bf16 LDS byte-image in workspace ----------------
// One-shot (~74K threads, ~0.15 MB written). Pads written as 0.
__global__ __launch_bounds__(256) void prep_kernel(
    const float* __restrict__ g0, const float* __restrict__ g1,
    const float* __restrict__ g2, const float* __restrict__ g3,
    u16* __restrict__ img)
{
  int t = (int)blockIdx.x * 256 + (int)threadIdx.x;
  if (t >= IMG_TOTAL) return;
  float val = 0.f;
  if (t < IMG_E0) {                         // c1: [n][j*16+i] <- g1[i][n][j]
    int n = t / MIDROW, r = t % MIDROW;
    if (r < 256) { int j = r >> 4, i = r & 15; val = g1[i * 2048 + n * 16 + j]; }
  } else if (t < IMG_E3) {                  // e0: [n][i] <- g0[0][n][i]
    int e = t - IMG_E0; int n = e / EROW, r = e % EROW;
    if (r < 16) val = g0[n * 16 + r];
  } else if (t < IMG_C2) {                  // e3: [n][i] <- g3[i][n][0]
    int e = t - IMG_E3; int n = e / EROW, r = e % EROW;
    if (r < 16) val = g3[r * NPT + n];
  } else {                                  // c2
    int e = t - IMG_C2; int n = e / MIDROW, r = e % MIDROW;
    if (r < 256) { int j = r >> 4, i = r & 15; val = g2[i * 2048 + n * 16 + j]; }
  }
  __hip_bfloat16 h = __float2bfloat16(val);
  img[t] = *(u16*)&h;
}

// async global->LDS, 16B per lane, 1 KiB per wave-issue (contiguous, conflict-free)
__device__ __forceinline__ void gload16(const u16* g, u16* l) {
  __builtin_amdgcn_global_load_lds(
      (const __attribute__((address_space(1))) uint32*)g,
      (__attribute__((address_space(3))) uint32*)l, 16, 0, 0);
}

// 512 threads, 1 point/thread, LDS = one mid core + both edges (79.9 KB) -> 2 blocks/CU.
// Stage c1 (+edges) via global_load_lds from prepped image, dims 0-1, restage c2, dims 2-3.
__global__ __launch_bounds__(512, 4) void tt_kernel(
    const float* __restrict__ x,  const float* __restrict__ g0,
    const float* __restrict__ g1, const float* __restrict__ g2,
    const float* __restrict__ g3, const u16* __restrict__ img,
    float* __restrict__ out, int npts)
{
  extern __shared__ char smem[];
  u16* mid = (u16*)smem;             // [128][264] bf16 (c1, then c2)
  u16* e0  = mid + MID_ELEMS;        // [128][24] bf16
  u16* e3  = e0 + EDGE_ELEMS;        // [128][24] bf16

  const int lane = (int)threadIdx.x & 63;
  const int wid  = (int)threadIdx.x >> 6;     // 0..7

  // ---- phase 0 staging: [c1 | e0 | e3] = one contiguous 79872 B image ----
  if (img) {
    for (int c = wid; c < PHASE0_CHUNKS; c += 8)
      gload16(img + c * 512 + lane * 8, mid + c * 512 + lane * 8);
  } else {
    // fallback (no workspace): convert in-kernel
    for (int t = (int)threadIdx.x; t < RNK * NPT * RNK; t += 512) {
      int i = t >> 11, n = (t >> 4) & (NPT - 1), j = t & 15;
      __hip_bfloat16 h = __float2bfloat16(g1[t]);
      mid[n * MIDROW + j * 16 + i] = *(u16*)&h;
    }
    for (int t = (int)threadIdx.x; t < NPT * RNK; t += 512) {
      int n = t >> 4, i = t & 15;
      __hip_bfloat16 a = __float2bfloat16(g0[t]);
      __hip_bfloat16 b = __float2bfloat16(g3[i * NPT + n]);
      e0[n * EROW + i] = *(u16*)&a;
      e3[n * EROW + i] = *(u16*)&b;
    }
  }
  __syncthreads();

  const int p = (int)blockIdx.x * 512 + (int)threadIdx.x;
  const bool active = p < npts;
  float4 xv = active ? reinterpret_cast<const float4*>(x)[p]
                     : make_float4(-1.f, -1.f, -1.f, -1.f);

  // ---- dim 0: lerp core0 row -> v[16] ----
  float v[16];
  {
    float xc = remap_clamp(xv.x);
    int n0 = (int)xc; float w = xc - (float)n0; int n1 = min(n0 + 1, NPT - 1);
    const uint4* L = (const uint4*)(e0 + n0 * EROW);
    const uint4* H = (const uint4*)(e0 + n1 * EROW);
    uint4 l0 = L[0], l1 = L[1], h0 = H[0], h1 = H[1];
    lerp8(l0, h0, w, v);
    lerp8(l1, h1, w, v + 8);
  }

  // ---- dim 1 ----
  tt_mid((const uint32*)mid, remap_clamp(xv.y), v);

  // ---- restage: c2 into same LDS buffer ----
  __syncthreads();                    // all waves done reading c1
  if (img) {
    for (int c = wid; c < PHASE1_CHUNKS; c += 8)
      gload16(img + IMG_C2 + c * 512 + lane * 8, mid + c * 512 + lane * 8);
  } else {
    for (int t = (int)threadIdx.x; t < RNK * NPT * RNK; t += 512) {
      int i = t >> 11, n = (t >> 4) & (NPT - 1), j = t & 15;
      __hip_bfloat16 h = __float2bfloat16(g2[t]);
      mid[n * MIDROW + j * 16 + i] = *(u16*)&h;
    }
  }
  __syncthreads();

  // ---- dim 2 ----
  tt_mid((const uint32*)mid, remap_clamp(xv.z), v);

  // ---- dim 3: dot with lerped core3 column ----
  float acc = 0.f;
  {
    float xc = remap_clamp(xv.w);
    int n0 = (int)xc; float w = xc - (float)n0; int n1 = min(n0 + 1, NPT - 1);
    const uint4* L = (const uint4*)(e3 + n0 * EROW);
    const uint4* H = (const uint4*)(e3 + n1 * EROW);
    float c3v[16];
    lerp8(L[0], H[0], w, c3v);
    lerp8(L[1], H[1], w, c3v + 8);
    float a0 = 0.f, a1 = 0.f, a2 = 0.f, a3 = 0.f;
#pragma unroll
    for (int k = 0; k < 4; ++k) {
      a0 = fmaf(v[4*k+0], c3v[4*k+0], a0);
      a1 = fmaf(v[4*k+1], c3v[4*k+1], a1);
      a2 = fmaf(v[4*k+2], c3v[4*k+2], a2);
      a3 = fmaf(v[4*k+3], c3v[4*k+3], a3);
    }
    acc = (a0 + a1) + (a2 + a3);
  }
  if (active) out[p] = acc;
}

extern "C" void kernel_launch(void* const* d_in, const int* in_sizes, int n_in,
                              void* d_out, int out_size, void* d_ws, size_t ws_size,
                              hipStream_t stream) {
  const float* x  = (const float*)d_in[0];
  const float* g0 = (const float*)d_in[1];
  const float* g1 = (const float*)d_in[2];
  const float* g2 = (const float*)d_in[3];
  const float* g3 = (const float*)d_in[4];
  float* out = (float*)d_out;

  int B = in_sizes[0] / 4;
  bool useimg = (d_ws != nullptr) && (ws_size >= (size_t)WS_BYTES);
  u16* img = useimg ? (u16*)d_ws : nullptr;

  if (useimg) {
    prep_kernel<<<(IMG_TOTAL + 255) / 256, 256, 0, stream>>>(g0, g1, g2, g3, img);
  }

  hipFuncSetAttribute(reinterpret_cast<const void*>(tt_kernel),
                      hipFuncAttributeMaxDynamicSharedMemorySize, SMEM_BYTES);
  int block = 512;
  int grid = (B + block - 1) / block;    // 512 blocks -> 2 per CU
  tt_kernel<<<grid, block, SMEM_BYTES, stream>>>(x, g0, g1, g2, g3, img, out, B);
}

// Round 3
// 124.344 us; speedup vs baseline: 1.0125x; 1.0125x over previous
//
#include <hip/hip_runtime.h>
#include <hip/hip_bf16.h>

typedef unsigned int uint32;
typedef unsigned short u16;

#define NPT 128        // grid nodes per dim
#define RNK 16         // TT rank
#define MIDROW 264     // bf16 elems per LDS row for mid cores (256 + 8 pad) = 528 B
#define MIDROW_U32 132
#define EROW 20        // fp32 elems per edge row (16 + 4 pad) = 80 B

// Byte image layout (built by prep_kernel, byte-exact copy of desired LDS):
//   [c1 bf16 67584 B][e0 f32 10240 B][e3 f32 10240 B][c2 bf16 67584 B]
#define OFF_E   67584
#define OFF_C2  88064
#define WS_BYTES 155648
#define SMEM_BYTES WS_BYTES
#define P0_CHUNKS (OFF_C2 / 1024)             // 86 x 1 KiB  (c1 + e0 + e3)
#define P1_CHUNKS ((WS_BYTES - OFF_C2) / 1024) // 66 x 1 KiB  (c2)

#if defined(__has_builtin)
#if __has_builtin(__builtin_amdgcn_fdot2_f32_bf16)
#define HAVE_BFDOT2 1
#endif
#endif

__device__ __forceinline__ float bl(uint32 u){ return __uint_as_float(u << 16); }
__device__ __forceinline__ float bh(uint32 u){ return __uint_as_float(u & 0xffff0000u); }

__device__ __forceinline__ uint32 pk2(float a, float b){
  __hip_bfloat16 l = __float2bfloat16(a);
  __hip_bfloat16 h = __float2bfloat16(b);
  return (uint32)(*(u16*)&l) | ((uint32)(*(u16*)&h) << 16);
}

#ifdef HAVE_BFDOT2
typedef __bf16 v2bf __attribute__((ext_vector_type(2)));
__device__ __forceinline__ v2bf bc(uint32 u){ return __builtin_bit_cast(v2bf, u); }

__device__ __forceinline__ float dot16b(const uint32* vp, uint4 U0, uint4 U1) {
  float s0 = 0.f, s1 = 0.f;
  s0 = __builtin_amdgcn_fdot2_f32_bf16(bc(vp[0]), bc(U0.x), s0, false);
  s0 = __builtin_amdgcn_fdot2_f32_bf16(bc(vp[1]), bc(U0.y), s0, false);
  s0 = __builtin_amdgcn_fdot2_f32_bf16(bc(vp[2]), bc(U0.z), s0, false);
  s0 = __builtin_amdgcn_fdot2_f32_bf16(bc(vp[3]), bc(U0.w), s0, false);
  s1 = __builtin_amdgcn_fdot2_f32_bf16(bc(vp[4]), bc(U1.x), s1, false);
  s1 = __builtin_amdgcn_fdot2_f32_bf16(bc(vp[5]), bc(U1.y), s1, false);
  s1 = __builtin_amdgcn_fdot2_f32_bf16(bc(vp[6]), bc(U1.z), s1, false);
  s1 = __builtin_amdgcn_fdot2_f32_bf16(bc(vp[7]), bc(U1.w), s1, false);
  return s0 + s1;
}
#else
__device__ __forceinline__ float dot16(const float* v, uint4 U0, uint4 U1) {
  float s0 = fmaf(v[1],  bh(U0.x), v[0]*bl(U0.x));
  s0 = fmaf(v[2],  bl(U0.y), s0); s0 = fmaf(v[3],  bh(U0.y), s0);
  float s1 = fmaf(v[5],  bh(U0.z), v[4]*bl(U0.z));
  s1 = fmaf(v[6],  bl(U0.w), s1); s1 = fmaf(v[7],  bh(U0.w), s1);
  float s2 = fmaf(v[9],  bh(U1.x), v[8]*bl(U1.x));
  s2 = fmaf(v[10], bl(U1.y), s2); s2 = fmaf(v[11], bh(U1.y), s2);
  float s3 = fmaf(v[13], bh(U1.z), v[12]*bl(U1.z));
  s3 = fmaf(v[14], bl(U1.w), s3); s3 = fmaf(v[15], bh(U1.w), s3);
  return (s0 + s1) + (s2 + s3);
}
#endif

__device__ __forceinline__ float remap_clamp(float x) {
  float xr = (x + 1.0f) * 0.5f * (float)(NPT - 1);
  return fminf(fmaxf(xr, 0.0f), (float)(NPT - 1));
}

// one middle-dim contraction: v <- v @ ((1-w)*Lo + w*Hi), rows in LDS as [n][j*16+i] bf16
__device__ __forceinline__ void tt_mid(const uint32* __restrict__ base, float xc, float v[16]) {
  int n0 = (int)xc;
  float w = xc - (float)n0;
  int n1 = min(n0 + 1, NPT - 1);
  const uint32* r0 = base + n0 * MIDROW_U32;
  const uint32* r1 = base + n1 * MIDROW_U32;

#ifdef HAVE_BFDOT2
  uint32 vp[8];
#pragma unroll
  for (int k = 0; k < 8; ++k) vp[k] = pk2(v[2*k], v[2*k+1]);
#endif

  float nv[16];
#pragma unroll
  for (int j = 0; j < 16; ++j) {
    const uint4* p0 = (const uint4*)(r0 + j * 8);
    const uint4* p1 = (const uint4*)(r1 + j * 8);
    uint4 A0 = p0[0], A1 = p0[1];
    uint4 B0 = p1[0], B1 = p1[1];
#ifdef HAVE_BFDOT2
    float a = dot16b(vp, A0, A1);
    float b = dot16b(vp, B0, B1);
#else
    float a = dot16(v, A0, A1);
    float b = dot16(v, B0, B1);
#endif
    nv[j] = fmaf(w, b - a, a);
  }
#pragma unroll
  for (int j = 0; j < 16; ++j) v[j] = nv[j];
}

// ---------------- prep: build the LDS byte-image in workspace (one-shot, tiny) ----------------
__global__ __launch_bounds__(256) void prep_kernel(
    const float* __restrict__ g0, const float* __restrict__ g1,
    const float* __restrict__ g2, const float* __restrict__ g3,
    char* __restrict__ img)
{
  int t = (int)blockIdx.x * 256 + (int)threadIdx.x;
  if (t < 67584) {                       // mid cores as bf16: c1 then c2
    int h = t >= 33792;
    int e = h ? t - 33792 : t;
    int n = e / MIDROW, r = e % MIDROW;
    float val = 0.f;
    if (r < 256) { int j = r >> 4, i = r & 15; val = (h ? g2 : g1)[i * 2048 + n * 16 + j]; }
    __hip_bfloat16 b = __float2bfloat16(val);
    ((u16*)img)[h ? (OFF_C2 / 2 + e) : e] = *(u16*)&b;
  } else if (t < 72704) {                // edges as fp32: e0 then e3, 20-float rows
    int e = t - 67584;                   // [0, 5120)
    int h = e >= 2560;
    int q = h ? e - 2560 : e;
    int n = q / EROW, k = q % EROW;
    float val = 0.f;
    if (k < 16) val = h ? g3[k * NPT + n] : g0[n * 16 + k];
    ((float*)(img + OFF_E))[e] = val;
  }
}

// async global->LDS, 16 B/lane, 1 KiB per wave-issue (contiguous, conflict-free)
__device__ __forceinline__ void gload16(const char* g, char* l) {
  __builtin_amdgcn_global_load_lds(
      (const __attribute__((address_space(1))) uint32*)g,
      (__attribute__((address_space(3))) uint32*)l, 16, 0, 0);
}

// 1024 threads, 1 point/thread, both mid cores resident (152 KB LDS, 1 block/CU).
// Stage c1+edges -> barrier -> ISSUE c2 loads -> dims 0-1 -> barrier (vmcnt drain
// publishes c2) -> dims 2-3. No mid-kernel global round-trip on the critical path.
__global__ __launch_bounds__(1024, 4) void tt_kernel(
    const float* __restrict__ x,  const float* __restrict__ g0,
    const float* __restrict__ g1, const float* __restrict__ g2,
    const float* __restrict__ g3, const char* __restrict__ img,
    float* __restrict__ out, int npts)
{
  extern __shared__ char smem[];
  u16* c1   = (u16*)smem;                 // [128][264] bf16
  float* e0 = (float*)(smem + OFF_E);     // [128][20] f32
  float* e3 = e0 + NPT * EROW;            // [128][20] f32
  u16* c2   = (u16*)(smem + OFF_C2);      // [128][264] bf16

  const int lane = (int)threadIdx.x & 63;
  const int wid  = (int)threadIdx.x >> 6;     // 0..15

  if (img) {
    // phase 0: c1 + e0 + e3 (86 KiB-chunks across 16 waves)
    for (int c = wid; c < P0_CHUNKS; c += 16)
      gload16(img + c * 1024 + lane * 16, smem + c * 1024 + lane * 16);
  } else {
    // fallback: in-kernel conversion (round-0 path)
    for (int t = (int)threadIdx.x; t < RNK * NPT * RNK; t += 1024) {
      int i = t >> 11, n = (t >> 4) & (NPT - 1), j = t & 15;
      __hip_bfloat16 h = __float2bfloat16(g1[t]);
      c1[n * MIDROW + j * 16 + i] = *(u16*)&h;
    }
    for (int t = (int)threadIdx.x; t < NPT * RNK; t += 1024) {
      int n = t >> 4, i = t & 15;
      e0[n * EROW + i] = g0[t];
      e3[n * EROW + i] = g3[i * NPT + n];
    }
  }
  __syncthreads();          // c1 + edges published (vmcnt drained by barrier)

  if (img) {
    // issue c2 loads now; they complete under dims 0-1 compute
    for (int c = wid; c < P1_CHUNKS; c += 16)
      gload16(img + OFF_C2 + c * 1024 + lane * 16, smem + OFF_C2 + c * 1024 + lane * 16);
  } else {
    for (int t = (int)threadIdx.x; t < RNK * NPT * RNK; t += 1024) {
      int i = t >> 11, n = (t >> 4) & (NPT - 1), j = t & 15;
      __hip_bfloat16 h = __float2bfloat16(g2[t]);
      c2[n * MIDROW + j * 16 + i] = *(u16*)&h;
    }
  }

  const int p = (int)blockIdx.x * 1024 + (int)threadIdx.x;
  const bool active = p < npts;
  float4 xv = active ? reinterpret_cast<const float4*>(x)[p]
                     : make_float4(-1.f, -1.f, -1.f, -1.f);

  // ---- dim 0: lerp core0 row -> v[16] (fp32 LDS) ----
  float v[16];
  {
    float xc = remap_clamp(xv.x);
    int n0 = (int)xc; float w = xc - (float)n0; int n1 = min(n0 + 1, NPT - 1);
    const float4* L = (const float4*)(e0 + n0 * EROW);
    const float4* H = (const float4*)(e0 + n1 * EROW);
#pragma unroll
    for (int k = 0; k < 4; ++k) {
      float4 l = L[k], h = H[k];
      v[4*k+0] = fmaf(w, h.x - l.x, l.x);
      v[4*k+1] = fmaf(w, h.y - l.y, l.y);
      v[4*k+2] = fmaf(w, h.z - l.z, l.z);
      v[4*k+3] = fmaf(w, h.w - l.w, l.w);
    }
  }

  // ---- dim 1 (c1) ----
  tt_mid((const uint32*)c1, remap_clamp(xv.y), v);

  __syncthreads();          // implicit vmcnt(0) drain: c2 now fully in LDS

  // ---- dim 2 (c2) ----
  tt_mid((const uint32*)c2, remap_clamp(xv.z), v);

  // ---- dim 3: dot with lerped core3 column (fp32 LDS) ----
  float acc;
  {
    float xc = remap_clamp(xv.w);
    int n0 = (int)xc; float w = xc - (float)n0; int n1 = min(n0 + 1, NPT - 1);
    const float4* L = (const float4*)(e3 + n0 * EROW);
    const float4* H = (const float4*)(e3 + n1 * EROW);
    float a0 = 0.f, a1 = 0.f, a2 = 0.f, a3 = 0.f;
#pragma unroll
    for (int k = 0; k < 4; ++k) {
      float4 l = L[k], h = H[k];
      a0 = fmaf(v[4*k+0], fmaf(w, h.x - l.x, l.x), a0);
      a1 = fmaf(v[4*k+1], fmaf(w, h.y - l.y, l.y), a1);
      a2 = fmaf(v[4*k+2], fmaf(w, h.z - l.z, l.z), a2);
      a3 = fmaf(v[4*k+3], fmaf(w, h.w - l.w, l.w), a3);
    }
    acc = (a0 + a1) + (a2 + a3);
  }
  if (active) out[p] = acc;
}

extern "C" void kernel_launch(void* const* d_in, const int* in_sizes, int n_in,
                              void* d_out, int out_size, void* d_ws, size_t ws_size,
                              hipStream_t stream) {
  const float* x  = (const float*)d_in[0];
  const float* g0 = (const float*)d_in[1];
  const float* g1 = (const float*)d_in[2];
  const float* g2 = (const float*)d_in[3];
  const float* g3 = (const float*)d_in[4];
  float* out = (float*)d_out;

  int B = in_sizes[0] / 4;
  bool useimg = (d_ws != nullptr) && (ws_size >= (size_t)WS_BYTES);
  char* img = useimg ? (char*)d_ws : nullptr;

  if (useimg) {
    prep_kernel<<<(72704 + 255) / 256, 256, 0, stream>>>(g0, g1, g2, g3, img);
  }

  hipFuncSetAttribute(reinterpret_cast<const void*>(tt_kernel),
                      hipFuncAttributeMaxDynamicSharedMemorySize, SMEM_BYTES);
  int block = 1024;
  int grid = (B + block - 1) / block;   // 256 blocks -> 1 per CU
  tt_kernel<<<grid, block, SMEM_BYTES, stream>>>(x, g0, g1, g2, g3, img, out, B);
}